// Round 5
// baseline (61.966 us; speedup 1.0000x reference)
//
#include <hip/hip_runtime.h>
#include <hip/hip_bf16.h>

// SpiralConv: out[n][o] = sum_{s,c} x[idx[n][s]][c] * W[o][s*32+c] + b[o]
// N=163842, SEQ=9, IN_CH=32, OUT_CH=64.
// Round 5: K-split gather working set to fit per-XCD L2 (4 MiB).
//   xk[4][NN][8] bf16  (2.62 MB per array)  <- gathers become L2-resident
//   wk[4][12][64][8] bf16 zero-padded       <- staged in LDS, padded stride
// MFMA k=32 repacked as (4 neighbors x 8 channels); acc over ka in registers.

constexpr int NN   = 163842;
constexpr int SEQ  = 9;
constexpr int INC  = 32;
constexpr int OUTC = 64;
constexpr int FAN  = SEQ * INC;          // 288
constexpr int NKA  = 4;                  // K-split arrays
constexpr int KC   = 8;                  // channels per array
constexpr int SPAD = 12;                 // seq padded to 3 groups of 4
constexpr int SROW = 64 * 16 + 64;       // 1088 B LDS stride per (ka,s) W row
constexpr int WTOT = NKA * SPAD * OUTC * KC;  // 24576 elems = 48 KB

using s8    = __attribute__((ext_vector_type(8))) short;   // 8 bf16
using f32x4 = __attribute__((ext_vector_type(4))) float;

__device__ __forceinline__ unsigned f2bf(float f) {
    union { float f; unsigned u; } c; c.f = f;
    unsigned u = c.u;
    u += 0x7fffu + ((u >> 16) & 1u);   // RNE
    return (u >> 16) & 0xffffu;
}

// One kernel: convert x into 4 K-split bf16 arrays + pack W (zero-padded).
__global__ __launch_bounds__(256) void convert_pack_kernel(
    const float* __restrict__ x, const float* __restrict__ W,
    unsigned short* __restrict__ xk,      // [4][NN][8]
    unsigned short* __restrict__ wk)      // [4][12][64][8]
{
    const int t   = blockIdx.x * blockDim.x + threadIdx.x;
    const int xq2 = NN * 2;
    if (t < xq2) {
        const int n = t >> 1, h = t & 1;       // h = channel half (16 ch)
        const float4* px = reinterpret_cast<const float4*>(x + (size_t)n * INC + h * 16);
        float4 a = px[0], b = px[1], c = px[2], d = px[3];
        uint4 lo, hi;
        lo.x = f2bf(a.x) | (f2bf(a.y) << 16);
        lo.y = f2bf(a.z) | (f2bf(a.w) << 16);
        lo.z = f2bf(b.x) | (f2bf(b.y) << 16);
        lo.w = f2bf(b.z) | (f2bf(b.w) << 16);
        hi.x = f2bf(c.x) | (f2bf(c.y) << 16);
        hi.y = f2bf(c.z) | (f2bf(c.w) << 16);
        hi.z = f2bf(d.x) | (f2bf(d.y) << 16);
        hi.w = f2bf(d.z) | (f2bf(d.w) << 16);
        // channels h*16+0..7 -> array 2h ; +8..15 -> array 2h+1
        reinterpret_cast<uint4*>(xk)[(size_t)(2 * h)     * NN + n] = lo;
        reinterpret_cast<uint4*>(xk)[(size_t)(2 * h + 1) * NN + n] = hi;
    } else if (t < xq2 + WTOT) {
        const int j  = t - xq2;                 // [ka][s][o][c] linear
        const int c  = j & 7;
        const int o  = (j >> 3) & 63;
        const int r  = j >> 9;                  // ka*12 + s
        const int s  = r % SPAD;
        const int ka = r / SPAD;
        float v = (s < SEQ) ? W[(size_t)o * FAN + s * INC + ka * KC + c] : 0.0f;
        wk[j] = (unsigned short)f2bf(v);
    }
}

// Block = 256 = 4 waves; wave = 32 nodes x 64 outs. ka-loop keeps acc in regs.
// A-frag: lane(lc,lk) reads wk_lds[ka][s=g*4+lk][o=f*16+lc][0..8)  (16B)
// B-frag: lane(lc,lk) gathers xk[ka][ idx[node=base+lc][min(g*4+lk,8)] ][0..8)
// D[row=o][col=node]: reg r -> o = f*16 + lk*4 + r, node = base + lc.
__global__ __launch_bounds__(256) void spiral_gemm_kernel(
    const int* __restrict__ idx,              // [NN][SEQ] int32
    const unsigned short* __restrict__ xk,    // [4][NN][8] bf16
    const unsigned short* __restrict__ wk,    // [4][12][64][8] bf16
    const float* __restrict__ bias,           // [OUTC]
    float* __restrict__ out)                  // [NN][OUTC]
{
    __shared__ unsigned char wlds[NKA * SPAD * SROW];   // 52224 B

    const int tid  = threadIdx.x;
    const int lane = tid & 63;
    const int wid  = tid >> 6;
    const int lc   = lane & 15;
    const int lk   = lane >> 4;

    // ---- stage packed W -> LDS (padded s-stride; coalesced 16B chunks) ----
    {
        const uint4* w4 = reinterpret_cast<const uint4*>(wk);   // 3072 chunks
        #pragma unroll
        for (int k = 0; k < 12; ++k) {
            int i4   = tid + k * 256;          // 0..3071
            int ka   = i4 / (SPAD * 64);
            int r    = i4 - ka * (SPAD * 64);
            int s    = r >> 6, o = r & 63;
            *reinterpret_cast<uint4*>(&wlds[(ka * SPAD + s) * SROW + o * 16]) = w4[i4];
        }
    }

    // ---- indices (before barrier, overlaps staging) ----
    const int nodeBase = blockIdx.x * 128 + wid * 32;
    const int nd0 = min(nodeBase + lc,      NN - 1);
    const int nd1 = min(nodeBase + 16 + lc, NN - 1);
    int iv0[3], iv1[3];
    #pragma unroll
    for (int g = 0; g < 3; ++g) {
        int s = g * 4 + lk; if (s > 8) s = 8;   // dup row; W-pad is zero
        iv0[g] = idx[(size_t)nd0 * SEQ + s];
        iv1[g] = idx[(size_t)nd1 * SEQ + s];
    }
    __syncthreads();

    // ---- ka loop: gathers hit L2-resident 2.62MB array ----
    f32x4 acc[2][4] = {};
    #pragma unroll
    for (int ka = 0; ka < NKA; ++ka) {
        const unsigned short* xa = xk + (size_t)ka * NN * KC;
        s8 b0[3], b1[3];
        #pragma unroll
        for (int g = 0; g < 3; ++g) {
            b0[g] = *reinterpret_cast<const s8*>(xa + (size_t)iv0[g] * KC);
            b1[g] = *reinterpret_cast<const s8*>(xa + (size_t)iv1[g] * KC);
        }
        #pragma unroll
        for (int g = 0; g < 3; ++g) {
            #pragma unroll
            for (int f = 0; f < 4; ++f) {
                const int s = g * 4 + lk;
                s8 wf = *reinterpret_cast<const s8*>(
                    &wlds[(ka * SPAD + s) * SROW + (f * 16 + lc) * 16]);
                acc[0][f] = __builtin_amdgcn_mfma_f32_16x16x32_bf16(wf, b0[g], acc[0][f], 0, 0, 0);
                acc[1][f] = __builtin_amdgcn_mfma_f32_16x16x32_bf16(wf, b1[g], acc[1][f], 0, 0, 0);
            }
        }
    }

    // ---- epilogue: bias + float4 stores ----
    #pragma unroll
    for (int f = 0; f < 4; ++f) {
        const f32x4 b4 = *reinterpret_cast<const f32x4*>(bias + f * 16 + lk * 4);
        #pragma unroll
        for (int m = 0; m < 2; ++m) {
            const int node = nodeBase + m * 16 + lc;
            if (node < NN) {
                f32x4 v = acc[m][f] + b4;
                *reinterpret_cast<f32x4*>(out + (size_t)node * OUTC + f * 16 + lk * 4) = v;
            }
        }
    }
}

extern "C" void kernel_launch(void* const* d_in, const int* in_sizes, int n_in,
                              void* d_out, int out_size, void* d_ws, size_t ws_size,
                              hipStream_t stream) {
    const float* x    = (const float*)d_in[0];
    const int*   idx  = (const int*)d_in[1];
    const float* W    = (const float*)d_in[2];
    const float* b    = (const float*)d_in[3];
    float*       out  = (float*)d_out;

    unsigned short* xk = (unsigned short*)d_ws;              // 4*NN*8*2B = 10.49 MB
    unsigned short* wk = xk + (size_t)NKA * NN * KC;         // 48 KB, 16B-aligned

    const int ctot = NN * 2 + WTOT;
    convert_pack_kernel<<<(ctot + 255) / 256, 256, 0, stream>>>(x, W, xk, wk);

    const int nblocks = (NN + 127) / 128;                    // 1281
    spiral_gemm_kernel<<<nblocks, 256, 0, stream>>>(idx, xk, wk, b, out);
}

// Round 6
// 42.865 us; speedup vs baseline: 1.4456x; 1.4456x over previous
//
#include <hip/hip_runtime.h>
#include <hip/hip_bf16.h>

// SpiralConv: out[n][o] = sum_{s,c} x[idx[n][s]][c] * W[o][s*32+c] + b[o]
// N=163842, SEQ=9, IN_CH=32, OUT_CH=64.
// Round 6: persistent blocks + per-wave cross-tile software pipeline.
// Gather wall (~2.3 TB/s random 64B over 10.5MB bf16 xb) is compulsory;
// hide stores/idx/W/MFMA + latency under it. W packed [s][k4][o][8ch] ->
// LDS reads are contiguous per quarter-wave (conflict-free), staged once
// per block (amortized over TPB tiles).

constexpr int NN   = 163842;
constexpr int SEQ  = 9;
constexpr int INC  = 32;
constexpr int OUTC = 64;
constexpr int FAN  = SEQ * INC;            // 288
constexpr int NTILES = (NN + 63) / 64;     // 2561 (block=4 waves x 16 nodes)
constexpr int TPB  = 6;                    // tiles per block
constexpr int WELEM = SEQ * 4 * OUTC * 8;  // 18432 bf16 = 36 KB

using s8    = __attribute__((ext_vector_type(8))) short;   // 8 bf16
using f32x4 = __attribute__((ext_vector_type(4))) float;

__device__ __forceinline__ unsigned f2bf(float f) {
    union { float f; unsigned u; } c; c.f = f;
    unsigned u = c.u;
    u += 0x7fffu + ((u >> 16) & 1u);   // RNE
    return (u >> 16) & 0xffffu;
}

// Convert x -> bf16 xb, and pack W -> wpk[s][k4][o][c8] (bf16).
__global__ __launch_bounds__(256) void convert_pack_kernel(
    const float* __restrict__ x, const float* __restrict__ W,
    unsigned short* __restrict__ xb, unsigned short* __restrict__ wpk)
{
    const int xq = NN * INC / 4;           // 1,310,736 float4s
    int t = blockIdx.x * blockDim.x + threadIdx.x;
    if (t < xq) {
        float4 v = reinterpret_cast<const float4*>(x)[t];
        unsigned lo = f2bf(v.x) | (f2bf(v.y) << 16);
        unsigned hi = f2bf(v.z) | (f2bf(v.w) << 16);
        reinterpret_cast<uint2*>(xb)[t] = make_uint2(lo, hi);
    } else if (t < xq + WELEM / 4) {
        int j4 = t - xq;                   // 4 elems per thread
        int c4 = j4 & 1, o = (j4 >> 1) & 63, k4 = (j4 >> 7) & 3, s = j4 >> 9;
        float4 v = *reinterpret_cast<const float4*>(
            W + (size_t)o * FAN + s * INC + k4 * 8 + c4 * 4);
        unsigned lo = f2bf(v.x) | (f2bf(v.y) << 16);
        unsigned hi = f2bf(v.z) | (f2bf(v.w) << 16);
        reinterpret_cast<uint2*>(wpk)[j4] = make_uint2(lo, hi);
    }
}

// Persistent gather-GEMM. Block = 256 = 4 waves; wave = 16 nodes/tile;
// block tile = 64 nodes; TPB tiles per block, double-buffered pipeline.
__global__ __launch_bounds__(256) void spiral_gemm_kernel(
    const int* __restrict__ idx,              // [NN][SEQ] int32
    const unsigned short* __restrict__ xb,    // [NN][INC] bf16
    const unsigned short* __restrict__ wpk,   // [SEQ][4][64][8] bf16
    const float* __restrict__ bias,           // [OUTC]
    float* __restrict__ out)                  // [NN][OUTC]
{
    __shared__ unsigned short wlds[WELEM];    // 36 KB

    const int tid  = threadIdx.x;
    const int lane = tid & 63;
    const int wid  = tid >> 6;
    const int lc   = lane & 15;
    const int lk   = lane >> 4;
    const int kb   = lk * 8;

    // ---- stage packed W -> LDS once (2304 uint4, 9 per thread) ----
    {
        const uint4* s4 = reinterpret_cast<const uint4*>(wpk);
        uint4* d4 = reinterpret_cast<uint4*>(wlds);
        #pragma unroll
        for (int k = 0; k < 9; ++k) d4[tid + k * 256] = s4[tid + k * 256];
    }

    // bias for this lane's 4 outs (hoisted)
    f32x4 b4[4];
    #pragma unroll
    for (int f = 0; f < 4; ++f)
        b4[f] = *reinterpret_cast<const f32x4*>(bias + f * 16 + lk * 4);

    __syncthreads();

    const int t0    = blockIdx.x * TPB;
    const int lastT = min(t0 + TPB, NTILES) - 1;

    int iA[SEQ], iB[SEQ];
    s8  fA[SEQ], fB[SEQ];

    auto loadIdx = [&](int t, int (&iv)[SEQ]) {
        const int node = min(t * 64 + wid * 16 + lc, NN - 1);
        const int* ip = idx + (size_t)node * SEQ;
        #pragma unroll
        for (int s = 0; s < SEQ; ++s) iv[s] = ip[s];
    };
    auto gath = [&](const int (&iv)[SEQ], s8 (&xf)[SEQ]) {
        #pragma unroll
        for (int s = 0; s < SEQ; ++s)
            xf[s] = *reinterpret_cast<const s8*>(xb + (size_t)iv[s] * INC + kb);
    };
    auto computeStore = [&](int t, const s8 (&xf)[SEQ]) {
        f32x4 acc[4] = {};
        #pragma unroll
        for (int s = 0; s < SEQ; ++s) {
            #pragma unroll
            for (int f = 0; f < 4; ++f) {
                s8 wf = *reinterpret_cast<const s8*>(
                    &wlds[(((s * 4 + lk) * 64) + (f * 16 + lc)) * 8]);
                acc[f] = __builtin_amdgcn_mfma_f32_16x16x32_bf16(wf, xf[s], acc[f], 0, 0, 0);
            }
        }
        const int node = t * 64 + wid * 16 + lc;
        if (node < NN) {
            #pragma unroll
            for (int f = 0; f < 4; ++f) {
                f32x4 v = acc[f] + b4[f];
                *reinterpret_cast<f32x4*>(out + (size_t)node * OUTC + f * 16 + lk * 4) = v;
            }
        }
    };

    // ---- prologue ----
    loadIdx(t0, iA);
    gath(iA, fA);                       // tile t0 gathers in flight
    if (t0 + 1 <= lastT) loadIdx(t0 + 1, iB);

    // ---- pipelined main loop (TPB even; buffers statically indexed) ----
    #pragma unroll
    for (int k = 0; k < TPB; k += 2) {
        const int tB = t0 + k + 1, tA2 = t0 + k + 2, tB2 = t0 + k + 3;
        if (tB  <= lastT) gath(iB, fB);          // t+1 gathers in flight
        if (tA2 <= lastT) loadIdx(tA2, iA);      // t+2 idx in flight
        computeStore(t0 + k, fA);                // consume tile t
        if (tA2 <= lastT) gath(iA, fA);          // t+2 gathers in flight
        if (tB2 <= lastT) loadIdx(tB2, iB);      // t+3 idx in flight
        if (tB  <= lastT) computeStore(tB, fB);  // consume tile t+1
    }
}

extern "C" void kernel_launch(void* const* d_in, const int* in_sizes, int n_in,
                              void* d_out, int out_size, void* d_ws, size_t ws_size,
                              hipStream_t stream) {
    const float* x    = (const float*)d_in[0];
    const int*   idx  = (const int*)d_in[1];
    const float* W    = (const float*)d_in[2];
    const float* b    = (const float*)d_in[3];
    float*       out  = (float*)d_out;

    unsigned short* xb  = (unsigned short*)d_ws;           // NN*32 bf16 = 10.49 MB
    unsigned short* wpk = xb + (size_t)NN * INC;           // 36 KB, 16B-aligned

    const int ctot = NN * INC / 4 + WELEM / 4;
    convert_pack_kernel<<<(ctot + 255) / 256, 256, 0, stream>>>(x, W, xb, wpk);

    const int nblocks = (NTILES + TPB - 1) / TPB;          // 427
    spiral_gemm_kernel<<<nblocks, 256, 0, stream>>>(idx, xb, wpk, b, out);
}

// Round 7
// 42.795 us; speedup vs baseline: 1.4480x; 1.0016x over previous
//
#include <hip/hip_runtime.h>
#include <hip/hip_bf16.h>

// SpiralConv: out[n][o] = sum_{s,c} x[idx[n][s]][c] * W[o][s*32+c] + b[o]
// N=163842, SEQ=9, IN_CH=32, OUT_CH=64.
// Round 7: recover occupancy while keeping W-LDS amortization.
//   Block = 512 thr (8 waves) x 1 tile of 128 nodes, grid = 1281.
//   launch_bounds(512,6) -> >=3 blocks/CU resident = 24 waves/CU (3.6x R6).
//   Full 9-gather prefetch per wave; TLP replaces the R6 cross-tile ILP.
// Gather wall = random 64B rows from 10.5MB bf16 xb; parallelism-sensitive
// (R6 proved it), so more outstanding misses -> more throughput.

constexpr int NN   = 163842;
constexpr int SEQ  = 9;
constexpr int INC  = 32;
constexpr int OUTC = 64;
constexpr int FAN  = SEQ * INC;            // 288
constexpr int WELEM = SEQ * 4 * OUTC * 8;  // 18432 bf16 = 36 KB

using s8    = __attribute__((ext_vector_type(8))) short;   // 8 bf16
using f32x4 = __attribute__((ext_vector_type(4))) float;

__device__ __forceinline__ unsigned f2bf(float f) {
    union { float f; unsigned u; } c; c.f = f;
    unsigned u = c.u;
    u += 0x7fffu + ((u >> 16) & 1u);   // RNE
    return (u >> 16) & 0xffffu;
}

// Convert x -> bf16 xb, pack W -> wpk[s][k4][o][c8] (bf16).
__global__ __launch_bounds__(256) void convert_pack_kernel(
    const float* __restrict__ x, const float* __restrict__ W,
    unsigned short* __restrict__ xb, unsigned short* __restrict__ wpk)
{
    const int xq = NN * INC / 4;           // 1,310,736 float4s
    int t = blockIdx.x * blockDim.x + threadIdx.x;
    if (t < xq) {
        float4 v = reinterpret_cast<const float4*>(x)[t];
        unsigned lo = f2bf(v.x) | (f2bf(v.y) << 16);
        unsigned hi = f2bf(v.z) | (f2bf(v.w) << 16);
        reinterpret_cast<uint2*>(xb)[t] = make_uint2(lo, hi);
    } else if (t < xq + WELEM / 4) {
        int j4 = t - xq;                   // 4 elems per thread
        int c4 = j4 & 1, o = (j4 >> 1) & 63, k4 = (j4 >> 7) & 3, s = j4 >> 9;
        float4 v = *reinterpret_cast<const float4*>(
            W + (size_t)o * FAN + s * INC + k4 * 8 + c4 * 4);
        unsigned lo = f2bf(v.x) | (f2bf(v.y) << 16);
        unsigned hi = f2bf(v.z) | (f2bf(v.w) << 16);
        reinterpret_cast<uint2*>(wpk)[j4] = make_uint2(lo, hi);
    }
}

// Gather-GEMM. Block = 512 thr = 8 waves; wave = 16 nodes x 64 outs.
// A-frag: wlds[s][lk][o=f*16+lc][0..8) (16B contiguous per lane).
// B-frag: gather xb row of idx[node][s], 16B chunk kb=lk*8.
// D[row=o][col=node]: reg r -> o=f*16+lk*4+r, node=base+lc -> float4 store.
__global__ __launch_bounds__(512, 6) void spiral_gemm_kernel(
    const int* __restrict__ idx,              // [NN][SEQ] int32
    const unsigned short* __restrict__ xb,    // [NN][INC] bf16
    const unsigned short* __restrict__ wpk,   // [SEQ][4][64][8] bf16
    const float* __restrict__ bias,           // [OUTC]
    float* __restrict__ out)                  // [NN][OUTC]
{
    __shared__ unsigned short wlds[WELEM];    // 36 KB

    const int tid  = threadIdx.x;
    const int lane = tid & 63;
    const int wid  = tid >> 6;                // 0..7
    const int lc   = lane & 15;
    const int lk   = lane >> 4;
    const int kb   = lk * 8;

    // ---- stage packed W -> LDS once (2304 uint4 over 512 threads) ----
    {
        const uint4* s4 = reinterpret_cast<const uint4*>(wpk);
        uint4* d4 = reinterpret_cast<uint4*>(wlds);
        #pragma unroll
        for (int k = 0; k < 5; ++k) {
            int i = tid + k * 512;
            if (i < WELEM / 8) d4[i] = s4[i];
        }
    }

    // ---- idx + gathers (issued before the barrier; LDS store is to a
    //      different resource, gathers overlap the staging wait) ----
    const int node = blockIdx.x * 128 + wid * 16 + lc;
    const int nd   = min(node, NN - 1);
    const int* ip  = idx + (size_t)nd * SEQ;

    int iv[SEQ];
    #pragma unroll
    for (int s = 0; s < SEQ; ++s) iv[s] = ip[s];

    s8 xf[SEQ];
    #pragma unroll
    for (int s = 0; s < SEQ; ++s)
        xf[s] = *reinterpret_cast<const s8*>(xb + (size_t)iv[s] * INC + kb);

    __syncthreads();

    // ---- MFMA: W frags from LDS ----
    f32x4 acc[4] = {};
    #pragma unroll
    for (int s = 0; s < SEQ; ++s) {
        #pragma unroll
        for (int f = 0; f < 4; ++f) {
            s8 wf = *reinterpret_cast<const s8*>(
                &wlds[(((s * 4 + lk) * 64) + (f * 16 + lc)) * 8]);
            acc[f] = __builtin_amdgcn_mfma_f32_16x16x32_bf16(wf, xf[s], acc[f], 0, 0, 0);
        }
    }

    // ---- epilogue: bias + float4 stores ----
    if (node < NN) {
        #pragma unroll
        for (int f = 0; f < 4; ++f) {
            f32x4 b4 = *reinterpret_cast<const f32x4*>(bias + f * 16 + lk * 4);
            f32x4 v = acc[f] + b4;
            *reinterpret_cast<f32x4*>(out + (size_t)node * OUTC + f * 16 + lk * 4) = v;
        }
    }
}

extern "C" void kernel_launch(void* const* d_in, const int* in_sizes, int n_in,
                              void* d_out, int out_size, void* d_ws, size_t ws_size,
                              hipStream_t stream) {
    const float* x    = (const float*)d_in[0];
    const int*   idx  = (const int*)d_in[1];
    const float* W    = (const float*)d_in[2];
    const float* b    = (const float*)d_in[3];
    float*       out  = (float*)d_out;

    unsigned short* xb  = (unsigned short*)d_ws;           // NN*32 bf16 = 10.49 MB
    unsigned short* wpk = xb + (size_t)NN * INC;           // 36 KB, 16B-aligned

    const int ctot = NN * INC / 4 + WELEM / 4;
    convert_pack_kernel<<<(ctot + 255) / 256, 256, 0, stream>>>(x, W, xb, wpk);

    const int nblocks = (NN + 127) / 128;                  // 1281
    spiral_gemm_kernel<<<nblocks, 512, 0, stream>>>(idx, xb, wpk, b, out);
}

// Round 8
// 42.568 us; speedup vs baseline: 1.4557x; 1.0053x over previous
//
#include <hip/hip_runtime.h>
#include <hip/hip_bf16.h>

// SpiralConv: out[n][o] = sum_{s,c} x[idx[n][s]][c] * W[o][s*32+c] + b[o]
// N=163842, SEQ=9, IN_CH=32, OUT_CH=64.
// Round 8: R7 structure + ONE change: nontemporal stores for `out`
// (42 MB write-allocate stream was evicting the 10.5MB xb gather set from
// per-XCD L2). Isolated A/B vs R7's 42.79us. Everything else identical.

constexpr int NN   = 163842;
constexpr int SEQ  = 9;
constexpr int INC  = 32;
constexpr int OUTC = 64;
constexpr int FAN  = SEQ * INC;            // 288
constexpr int WELEM = SEQ * 4 * OUTC * 8;  // 18432 bf16 = 36 KB

using s8    = __attribute__((ext_vector_type(8))) short;   // 8 bf16
using f32x4 = __attribute__((ext_vector_type(4))) float;

__device__ __forceinline__ unsigned f2bf(float f) {
    union { float f; unsigned u; } c; c.f = f;
    unsigned u = c.u;
    u += 0x7fffu + ((u >> 16) & 1u);   // RNE
    return (u >> 16) & 0xffffu;
}

// Convert x -> bf16 xb, pack W -> wpk[s][k4][o][c8] (bf16).
__global__ __launch_bounds__(256) void convert_pack_kernel(
    const float* __restrict__ x, const float* __restrict__ W,
    unsigned short* __restrict__ xb, unsigned short* __restrict__ wpk)
{
    const int xq = NN * INC / 4;           // 1,310,736 float4s
    int t = blockIdx.x * blockDim.x + threadIdx.x;
    if (t < xq) {
        float4 v = reinterpret_cast<const float4*>(x)[t];
        unsigned lo = f2bf(v.x) | (f2bf(v.y) << 16);
        unsigned hi = f2bf(v.z) | (f2bf(v.w) << 16);
        reinterpret_cast<uint2*>(xb)[t] = make_uint2(lo, hi);
    } else if (t < xq + WELEM / 4) {
        int j4 = t - xq;                   // 4 elems per thread
        int c4 = j4 & 1, o = (j4 >> 1) & 63, k4 = (j4 >> 7) & 3, s = j4 >> 9;
        float4 v = *reinterpret_cast<const float4*>(
            W + (size_t)o * FAN + s * INC + k4 * 8 + c4 * 4);
        unsigned lo = f2bf(v.x) | (f2bf(v.y) << 16);
        unsigned hi = f2bf(v.z) | (f2bf(v.w) << 16);
        reinterpret_cast<uint2*>(wpk)[j4] = make_uint2(lo, hi);
    }
}

// Gather-GEMM. Block = 512 thr = 8 waves; wave = 16 nodes x 64 outs.
__global__ __launch_bounds__(512, 6) void spiral_gemm_kernel(
    const int* __restrict__ idx,              // [NN][SEQ] int32
    const unsigned short* __restrict__ xb,    // [NN][INC] bf16
    const unsigned short* __restrict__ wpk,   // [SEQ][4][64][8] bf16
    const float* __restrict__ bias,           // [OUTC]
    float* __restrict__ out)                  // [NN][OUTC]
{
    __shared__ unsigned short wlds[WELEM];    // 36 KB

    const int tid  = threadIdx.x;
    const int lane = tid & 63;
    const int wid  = tid >> 6;                // 0..7
    const int lc   = lane & 15;
    const int lk   = lane >> 4;
    const int kb   = lk * 8;

    // ---- stage packed W -> LDS once (2304 uint4 over 512 threads) ----
    {
        const uint4* s4 = reinterpret_cast<const uint4*>(wpk);
        uint4* d4 = reinterpret_cast<uint4*>(wlds);
        #pragma unroll
        for (int k = 0; k < 5; ++k) {
            int i = tid + k * 512;
            if (i < WELEM / 8) d4[i] = s4[i];
        }
    }

    // ---- idx + gathers (issued before the barrier) ----
    const int node = blockIdx.x * 128 + wid * 16 + lc;
    const int nd   = min(node, NN - 1);
    const int* ip  = idx + (size_t)nd * SEQ;

    int iv[SEQ];
    #pragma unroll
    for (int s = 0; s < SEQ; ++s) iv[s] = ip[s];

    s8 xf[SEQ];
    #pragma unroll
    for (int s = 0; s < SEQ; ++s)
        xf[s] = *reinterpret_cast<const s8*>(xb + (size_t)iv[s] * INC + kb);

    __syncthreads();

    // ---- MFMA: W frags from LDS ----
    f32x4 acc[4] = {};
    #pragma unroll
    for (int s = 0; s < SEQ; ++s) {
        #pragma unroll
        for (int f = 0; f < 4; ++f) {
            s8 wf = *reinterpret_cast<const s8*>(
                &wlds[(((s * 4 + lk) * 64) + (f * 16 + lc)) * 8]);
            acc[f] = __builtin_amdgcn_mfma_f32_16x16x32_bf16(wf, xf[s], acc[f], 0, 0, 0);
        }
    }

    // ---- epilogue: bias + NONTEMPORAL float4 stores (the one change) ----
    if (node < NN) {
        #pragma unroll
        for (int f = 0; f < 4; ++f) {
            f32x4 b4 = *reinterpret_cast<const f32x4*>(bias + f * 16 + lk * 4);
            f32x4 v = acc[f] + b4;
            __builtin_nontemporal_store(v,
                reinterpret_cast<f32x4*>(out + (size_t)node * OUTC + f * 16 + lk * 4));
        }
    }
}

extern "C" void kernel_launch(void* const* d_in, const int* in_sizes, int n_in,
                              void* d_out, int out_size, void* d_ws, size_t ws_size,
                              hipStream_t stream) {
    const float* x    = (const float*)d_in[0];
    const int*   idx  = (const int*)d_in[1];
    const float* W    = (const float*)d_in[2];
    const float* b    = (const float*)d_in[3];
    float*       out  = (float*)d_out;

    unsigned short* xb  = (unsigned short*)d_ws;           // NN*32 bf16 = 10.49 MB
    unsigned short* wpk = xb + (size_t)NN * INC;           // 36 KB, 16B-aligned

    const int ctot = NN * INC / 4 + WELEM / 4;
    convert_pack_kernel<<<(ctot + 255) / 256, 256, 0, stream>>>(x, W, xb, wpk);

    const int nblocks = (NN + 127) / 128;                  // 1281
    spiral_gemm_kernel<<<nblocks, 512, 0, stream>>>(idx, xb, wpk, b, out);
}